// Round 1
// baseline (2137.055 us; speedup 1.0000x reference)
//
#include <hip/hip_runtime.h>
#include <math.h>

#define BATCH 128
#define SLEN  8000
#define HID   64
#define CHUNK 64                  // steps per fc flush; 8000 = 125 * 64
#define NCHUNK (SLEN / CHUNK)     // 125
#define ROWSTRIDE 68              // floats; keeps b128 row reads conflict-free

__device__ __forceinline__ float fast_exp2(float x) { return __builtin_amdgcn_exp2f(x); }
__device__ __forceinline__ float fast_rcp(float x)  { return __builtin_amdgcn_rcpf(x); }

__device__ __forceinline__ float bcast_lane(float v, int lane) {
    return __int_as_float(__builtin_amdgcn_readlane(__float_as_int(v), lane));
}

// tanh(x) = sign(x) * (e - 1)/(e + 1), e = 2^(2|x|*log2 e)   (UNCHANGED - bitwise)
__device__ __forceinline__ float tanh_fast(float x) {
    float ax = fabsf(x);
    float z  = fminf(ax * 2.8853900817779268f, 30.0f);
    float e  = fast_exp2(z);
    float r  = (e - 1.0f) * fast_rcp(e + 1.0f);
    return x < 0.0f ? -r : r;
}

__device__ __forceinline__ float sigmoid_fast(float x) {
    float z = fminf(fmaxf(-x * 1.4426950408889634f, -60.0f), 60.0f);
    float e = fast_exp2(z);
    return fast_rcp(1.0f + e);
}

// h-broadcast via LDS instead of 64x v_readlane:
//   step r reads the full previous-h row ((r+63)&63) with 16x ds_read_b128,
//   all lanes at the SAME address -> LDS broadcast, 0 conflicts.
//   hbuf row r still holds h_t for the fc head, exactly as before.
__global__ __launch_bounds__(64) void rnn_lds_bcast_kernel(
    const float* __restrict__ x,      // [B, S]
    const float* __restrict__ W_ih,   // [H, 1]
    const float* __restrict__ b_ih,   // [H]
    const float* __restrict__ W_hh,   // [H, H]
    const float* __restrict__ b_hh,   // [H]
    const float* __restrict__ fc_w,   // [2, H]
    const float* __restrict__ fc_b,   // [2]
    float* __restrict__ out)          // [B]
{
    __shared__ float hbuf[CHUNK * ROWSTRIDE];   // 64 rows of h history

    const int lane = threadIdx.x;               // == hidden index i
    const int b    = blockIdx.x;
    const float* xrow = x + (size_t)b * SLEN;

    // Lane i holds W_hh row i: w[j] = W_hh[i][j]
    float w[HID];
    #pragma unroll
    for (int q = 0; q < 16; ++q) {
        float4 t = ((const float4*)(W_hh + lane * HID))[q];
        w[4*q+0] = t.x; w[4*q+1] = t.y; w[4*q+2] = t.z; w[4*q+3] = t.w;
    }
    const float wih  = W_ih[lane];
    const float bias = b_ih[lane] + b_hh[lane];
    const float fcb0 = fc_b[0], fcb1 = fc_b[1];

    float num = 0.0f, den = 0.0f;

    // h_{-1} = 0 lives in row 63 (read by step r=0 of chunk 0)
    hbuf[63 * ROWSTRIDE + lane] = 0.0f;

    float xv_next = xrow[lane];     // chunk 0's x values (one per lane)

    #pragma unroll 1
    for (int c = 0; c < NCHUNK; ++c) {
        float xcur = xv_next;
        // prefetch next chunk's x (off critical path; clamp index for last chunk)
        int nidx = (c + 1 < NCHUNK) ? (c + 1) * CHUNK + lane : lane;
        xv_next = xrow[nidx];

        #pragma unroll 4
        for (int r = 0; r < CHUNK; ++r) {
            float xv = bcast_lane(xcur, r);          // x_t (1 readlane/step, cheap)

            // broadcast-read previous h row: all lanes same address
            const float4* hp = (const float4*)(hbuf + ((r + 63) & 63) * ROWSTRIDE);
            float4 hreg[16];
            #pragma unroll
            for (int q = 0; q < 16; ++q) hreg[q] = hp[q];

            // EXACT same accumulation order as the readlane version:
            // acc[j&3] over ascending j, acc0 seeded with fma(wih, xv, bias)
            float acc0 = fmaf(wih, xv, bias);
            float acc1 = 0.0f, acc2 = 0.0f, acc3 = 0.0f;
            #pragma unroll
            for (int q = 0; q < 16; ++q) {
                acc0 = fmaf(w[4*q+0], hreg[q].x, acc0);
                acc1 = fmaf(w[4*q+1], hreg[q].y, acc1);
                acc2 = fmaf(w[4*q+2], hreg[q].z, acc2);
                acc3 = fmaf(w[4*q+3], hreg[q].w, acc3);
            }
            float a = (acc0 + acc1) + (acc2 + acc3);
            float h = tanh_fast(a);
            hbuf[r * ROWSTRIDE + lane] = h;          // feeds step r+1 AND the fc head
        }
        __syncthreads();   // single wave -> lgkmcnt drain only

        // fc head for the chunk: lane processes row `lane` (1 timestep per lane)
        {
            const float4* rp = (const float4*)(hbuf + lane * ROWSTRIDE);
            float d0 = 0.f, d1 = 0.f;
            #pragma unroll
            for (int q = 0; q < 16; ++q) {
                float4 hh = rp[q];
                float4 f0 = ((const float4*)fc_w)[q];          // uniform -> s_load
                float4 f1 = ((const float4*)(fc_w + HID))[q];
                d0 += hh.x * f0.x + hh.y * f0.y + hh.z * f0.z + hh.w * f0.w;
                d1 += hh.x * f1.x + hh.y * f1.y + hh.z * f1.z + hh.w * f1.w;
            }
            float sel = sigmoid_fast(d0 + fcb0);
            float sco = sigmoid_fast(d1 + fcb1);
            num = fmaf(sco, sel, num);
            den += sel;
        }
        __syncthreads();   // hbuf reads done before next chunk overwrites
    }

    // Final cross-lane reduction of (num, den)
    #pragma unroll
    for (int off = 32; off > 0; off >>= 1) {
        num += __shfl_down(num, off);
        den += __shfl_down(den, off);
    }
    if (lane == 0) out[b] = num / den;
}

extern "C" void kernel_launch(void* const* d_in, const int* in_sizes, int n_in,
                              void* d_out, int out_size, void* d_ws, size_t ws_size,
                              hipStream_t stream) {
    const float* x    = (const float*)d_in[0];
    const float* W_ih = (const float*)d_in[1];
    const float* b_ih = (const float*)d_in[2];
    const float* W_hh = (const float*)d_in[3];
    const float* b_hh = (const float*)d_in[4];
    const float* fc_w = (const float*)d_in[5];
    const float* fc_b = (const float*)d_in[6];
    float* out = (float*)d_out;

    rnn_lds_bcast_kernel<<<BATCH, 64, 0, stream>>>(x, W_ih, b_ih, W_hh, b_hh,
                                                   fc_w, fc_b, out);
}

// Round 2
// 2006.994 us; speedup vs baseline: 1.0648x; 1.0648x over previous
//
#include <hip/hip_runtime.h>
#include <math.h>

#define BATCH 128
#define SLEN  8000
#define HID   64
#define CHUNK 64                  // steps per fc flush; 8000 = 125 * 64
#define NCHUNK (SLEN / CHUNK)     // 125
#define ROWSTRIDE 68              // floats; keeps b128 row reads conflict-free

__device__ __forceinline__ float fast_exp2(float x) { return __builtin_amdgcn_exp2f(x); }
__device__ __forceinline__ float fast_rcp(float x)  { return __builtin_amdgcn_rcpf(x); }

__device__ __forceinline__ float bcast_lane(float v, int lane) {
    return __int_as_float(__builtin_amdgcn_readlane(__float_as_int(v), lane));
}

// tanh(x) = sign(x) * (e - 1)/(e + 1), e = 2^(2|x|*log2 e)   (UNCHANGED - bitwise)
__device__ __forceinline__ float tanh_fast(float x) {
    float ax = fabsf(x);
    float z  = fminf(ax * 2.8853900817779268f, 30.0f);
    float e  = fast_exp2(z);
    float r  = (e - 1.0f) * fast_rcp(e + 1.0f);
    return x < 0.0f ? -r : r;
}

__device__ __forceinline__ float sigmoid_fast(float x) {
    float z = fminf(fmaxf(-x * 1.4426950408889634f, -60.0f), 60.0f);
    float e = fast_exp2(z);
    return fast_rcp(1.0f + e);
}

// Round-0 structure (h stays in registers, readlane broadcast) but with the
// broadcast BATCHED: 16 independent v_readlane into 16 SGPRs, then 16 FMAs.
// This breaks the per-pair VALU-write-SGPR -> VALU-read-SGPR hazard that cost
// ~3 wait-state cycles x 64 per step in the tightly-interleaved version.
// Accumulation order (ascending j into acc[j&3]) is IDENTICAL -> bitwise-same output.
__global__ __launch_bounds__(64) void rnn_batched_readlane_kernel(
    const float* __restrict__ x,      // [B, S]
    const float* __restrict__ W_ih,   // [H, 1]
    const float* __restrict__ b_ih,   // [H]
    const float* __restrict__ W_hh,   // [H, H]
    const float* __restrict__ b_hh,   // [H]
    const float* __restrict__ fc_w,   // [2, H]
    const float* __restrict__ fc_b,   // [2]
    float* __restrict__ out)          // [B]
{
    __shared__ float hbuf[CHUNK * ROWSTRIDE];   // 64 rows of h history

    const int lane = threadIdx.x;               // == hidden index i
    const int b    = blockIdx.x;
    const float* xrow = x + (size_t)b * SLEN;

    // Lane i holds W_hh row i: w[j] = W_hh[i][j]  (64 VGPRs, const-indexed after unroll)
    float w[HID];
    #pragma unroll
    for (int q = 0; q < 16; ++q) {
        float4 t = ((const float4*)(W_hh + lane * HID))[q];
        w[4*q+0] = t.x; w[4*q+1] = t.y; w[4*q+2] = t.z; w[4*q+3] = t.w;
    }
    const float wih  = W_ih[lane];
    const float bias = b_ih[lane] + b_hh[lane];
    const float fcb0 = fc_b[0], fcb1 = fc_b[1];

    float h = 0.0f;                 // distributed hidden state: lane i holds h[i]
    float num = 0.0f, den = 0.0f;

    float xv_next = xrow[lane];     // chunk 0's x values (one per lane)

    #pragma unroll 1
    for (int c = 0; c < NCHUNK; ++c) {
        float xcur = xv_next;
        // prefetch next chunk's x (off critical path; clamp index for last chunk)
        int nidx = (c + 1 < NCHUNK) ? (c + 1) * CHUNK + lane : lane;
        xv_next = xrow[nidx];

        #pragma unroll 4
        for (int r = 0; r < CHUNK; ++r) {
            float xv = bcast_lane(xcur, r);          // x_t

            float acc[4];
            acc[0] = fmaf(wih, xv, bias);
            acc[1] = 0.0f; acc[2] = 0.0f; acc[3] = 0.0f;

            // 4 batches of 16: phase 1 = 16 independent readlanes (SGPRs),
            // phase 2 = 16 FMAs consuming them. Hazard distance >= 16.
            #pragma unroll
            for (int bb = 0; bb < 4; ++bb) {
                float hj[16];
                #pragma unroll
                for (int jj = 0; jj < 16; ++jj)
                    hj[jj] = bcast_lane(h, 16 * bb + jj);
                #pragma unroll
                for (int jj = 0; jj < 16; ++jj) {
                    int j = 16 * bb + jj;
                    acc[j & 3] = fmaf(w[j], hj[jj], acc[j & 3]);
                }
            }
            float a = (acc[0] + acc[1]) + (acc[2] + acc[3]);
            h = tanh_fast(a);
            hbuf[r * ROWSTRIDE + lane] = h;          // fire-and-forget, fc reads later
        }
        __syncthreads();   // single wave -> lgkmcnt drain only

        // fc head for the chunk: lane processes row `lane` (1 timestep per lane)
        {
            const float4* rp = (const float4*)(hbuf + lane * ROWSTRIDE);
            float d0 = 0.f, d1 = 0.f;
            #pragma unroll
            for (int q = 0; q < 16; ++q) {
                float4 hh = rp[q];
                float4 f0 = ((const float4*)fc_w)[q];          // uniform -> s_load
                float4 f1 = ((const float4*)(fc_w + HID))[q];
                d0 += hh.x * f0.x + hh.y * f0.y + hh.z * f0.z + hh.w * f0.w;
                d1 += hh.x * f1.x + hh.y * f1.y + hh.z * f1.z + hh.w * f1.w;
            }
            float sel = sigmoid_fast(d0 + fcb0);
            float sco = sigmoid_fast(d1 + fcb1);
            num = fmaf(sco, sel, num);
            den += sel;
        }
        __syncthreads();   // hbuf reads done before next chunk overwrites
    }

    // Final cross-lane reduction of (num, den)
    #pragma unroll
    for (int off = 32; off > 0; off >>= 1) {
        num += __shfl_down(num, off);
        den += __shfl_down(den, off);
    }
    if (lane == 0) out[b] = num / den;
}

extern "C" void kernel_launch(void* const* d_in, const int* in_sizes, int n_in,
                              void* d_out, int out_size, void* d_ws, size_t ws_size,
                              hipStream_t stream) {
    const float* x    = (const float*)d_in[0];
    const float* W_ih = (const float*)d_in[1];
    const float* b_ih = (const float*)d_in[2];
    const float* W_hh = (const float*)d_in[3];
    const float* b_hh = (const float*)d_in[4];
    const float* fc_w = (const float*)d_in[5];
    const float* fc_b = (const float*)d_in[6];
    float* out = (float*)d_out;

    rnn_batched_readlane_kernel<<<BATCH, 64, 0, stream>>>(x, W_ih, b_ih, W_hh, b_hh,
                                                          fc_w, fc_b, out);
}